// Round 3
// baseline (330.602 us; speedup 1.0000x reference)
//
#include <hip/hip_runtime.h>
#include <hip/hip_bf16.h>

#define IN_CH 4096
#define OUT_CH 11008

#define BM 128
#define BN 32
#define BK 64
#define KCHUNKS (IN_CH / BK)    // 64
#define NBLOCKS (OUT_CH / BN)   // 344
#define BPAD 72                  // B LDS row stride (64 + 8 pad)
#define XCONV_BLOCKS 64

typedef short bf16x8 __attribute__((ext_vector_type(8)));
typedef float f32x4 __attribute__((ext_vector_type(4)));

#define GLOBAL_AS __attribute__((address_space(1)))
#define LDS_AS __attribute__((address_space(3)))

__device__ inline unsigned short f2bf(float f) {
    union { __hip_bfloat16 h; unsigned short u; } cv;
    cv.h = __float2bfloat16(f);
    return cv.u;
}

// quantize-dequantize 8 fp32 weights by scale s (exact division, same math as
// the reference: q = clip(rint(w/s), -8, 7); out = bf16(q*s))
__device__ inline bf16x8 qdq8(float4 a, float4 b, float s) {
    bf16x8 o;
    const float v0 = a.x, v1 = a.y, v2 = a.z, v3 = a.w;
    const float v4 = b.x, v5 = b.y, v6 = b.z, v7 = b.w;
    o[0] = (short)f2bf(fminf(fmaxf(rintf(v0 / s), -8.0f), 7.0f) * s);
    o[1] = (short)f2bf(fminf(fmaxf(rintf(v1 / s), -8.0f), 7.0f) * s);
    o[2] = (short)f2bf(fminf(fmaxf(rintf(v2 / s), -8.0f), 7.0f) * s);
    o[3] = (short)f2bf(fminf(fmaxf(rintf(v3 / s), -8.0f), 7.0f) * s);
    o[4] = (short)f2bf(fminf(fmaxf(rintf(v4 / s), -8.0f), 7.0f) * s);
    o[5] = (short)f2bf(fminf(fmaxf(rintf(v5 / s), -8.0f), 7.0f) * s);
    o[6] = (short)f2bf(fminf(fmaxf(rintf(v6 / s), -8.0f), 7.0f) * s);
    o[7] = (short)f2bf(fminf(fmaxf(rintf(v7 / s), -8.0f), 7.0f) * s);
    return o;
}

// ---------------------------------------------------------------------------
// Kernel 1: x fp32 -> bf16 with XOR-swizzled granule layout:
//   xq[row][kc*64 + g*8 + t] = bf16(x[row][kc*64 + (g^(row&7))*8 + t])
// so global_load_lds's rigid lane->LDS mapping yields bank-conflict-free
// fragment reads in the GEMM.
// ---------------------------------------------------------------------------
__global__ __launch_bounds__(256) void xconv_kernel(
        const float* __restrict__ x, unsigned short* __restrict__ xq) {
    const int tid = threadIdx.x;
    const int bx = blockIdx.x;
    for (int it = 0; it < 4; ++it) {
        const int G = it * (XCONV_BLOCKS * 256) + bx * 256 + tid; // granule id
        const int row = G >> 9;                     // 512 granules/row
        const int gi = G & 511;                     // granule in row
        const int kc = gi >> 3;
        const int gp = gi & 7;
        const int gl = gp ^ (row & 7);              // logical granule
        const float4* src =
            (const float4*)(x + (size_t)row * IN_CH + kc * 64 + gl * 8);
        float4 a = src[0], b = src[1];
        ushort4 o0, o1;
        o0.x = f2bf(a.x); o0.y = f2bf(a.y); o0.z = f2bf(a.z); o0.w = f2bf(a.w);
        o1.x = f2bf(b.x); o1.y = f2bf(b.y); o1.z = f2bf(b.z); o1.w = f2bf(b.w);
        ushort4* dst = (ushort4*)(xq + (size_t)row * IN_CH + gi * 8);
        dst[0] = o0;
        dst[1] = o1;
    }
}

// ---------------------------------------------------------------------------
// Kernel 2: fully fused LPBQ quantize + dequant + GEMM + bias.
// Each block owns BN=32 out-channels for the full K=4096:
//   phase 1: stream the 32 weight rows (512 KB fp32), compute s1 per 64-block,
//            s2 per row, s1r in LDS (all reductions are row-local -> block-local)
//   phase 2: double-buffered K-loop; re-read w chunks (L3-resident, read
//            moments earlier), quantize-dequantize to bf16 B-tile in LDS;
//            A staged via global_load_lds w=16 from the swizzled xq; MFMA;
//            direct epilogue out = acc + bias (M=128 = BM: no K-split,
//            no partials, no reduce kernel, no wq materialization).
// ---------------------------------------------------------------------------
__global__ __launch_bounds__(256) void fused_kernel(
        const float* __restrict__ w, const unsigned short* __restrict__ A,
        const float* __restrict__ bias, float* __restrict__ out) {
    __shared__ float s1_lds[BN][KCHUNKS];                        // 8 KB
    __shared__ __align__(16) unsigned short ldsA[2][BM * BK];    // 32 KB
    __shared__ __align__(16) unsigned short ldsB[2][BN * BPAD];  // 9 KB

    const int tid = threadIdx.x;
    const int n0 = blockIdx.x * BN;

    const int prow = tid >> 3;        // 0..31: weight row within block
    const int pc8 = (tid & 7) * 8;    // 8-element column offset (also s1 cells)

    // ---------------- phase 1: s1 per (row, 64-block) ----------------
    const float* wrow = w + (size_t)(n0 + prow) * IN_CH + pc8;
#pragma unroll 4
    for (int c = 0; c < KCHUNKS; ++c) {
        float4 a = *(const float4*)(wrow + c * 64);
        float4 b = *(const float4*)(wrow + c * 64 + 4);
        float m = fmaxf(fmaxf(fabsf(a.x), fabsf(a.y)),
                        fmaxf(fabsf(a.z), fabsf(a.w)));
        m = fmaxf(m, fmaxf(fmaxf(fabsf(b.x), fabsf(b.y)),
                           fmaxf(fabsf(b.z), fabsf(b.w))));
        m = fmaxf(m, __shfl_xor(m, 1));
        m = fmaxf(m, __shfl_xor(m, 2));
        m = fmaxf(m, __shfl_xor(m, 4));
        if ((tid & 7) == 0)
            s1_lds[prow][c] = fmaxf(m * (1.0f / 7.0f), 1e-8f);
    }
    __syncthreads();

    // ---------------- s2 per row; s1r in place ----------------
    {
        float sv[8];
        float m = 0.0f;  // s1 >= 1e-8 > 0
#pragma unroll
        for (int k = 0; k < 8; ++k) {
            sv[k] = s1_lds[prow][pc8 + k];
            m = fmaxf(m, sv[k]);
        }
        m = fmaxf(m, __shfl_xor(m, 1));
        m = fmaxf(m, __shfl_xor(m, 2));
        m = fmaxf(m, __shfl_xor(m, 4));
        const float s2 = fmaxf(m * (1.0f / 15.0f), 1e-8f);
#pragma unroll
        for (int k = 0; k < 8; ++k) {
            const float s1q = fminf(fmaxf(rintf(sv[k] / s2), 0.0f), 15.0f);
            s1_lds[prow][pc8 + k] = s1q * s2;   // s1r
        }
    }
    __syncthreads();

    // ---------------- phase 2: double-buffered MFMA K-loop ----------------
    const int wid = tid >> 6;
    const int l = tid & 63;
    const int wm = wid >> 1;      // 0..1: 64-row half of A
    const int wn = wid & 1;       // 0..1: 16-col half of B
    const int r8 = l >> 3;        // A staging: row within 8-row group
    const int sg = l & 7;         // A staging: 16B segment in 128B row
    const int lane15 = l & 15;
    const int quad = l >> 4;

    const float* wB = w + (size_t)(n0 + prow) * IN_CH + pc8;  // B staging ptr

    f32x4 acc[4] = {};

    // prologue: stage chunk 0 into buffer 0
    {
        float4 b0 = *(const float4*)(wB);
        float4 b1 = *(const float4*)(wB + 4);
        for (int i = 0; i < 4; ++i) {
            const unsigned short* gp =
                A + (size_t)(i * 32 + wid * 8 + r8) * IN_CH + sg * 8;
            LDS_AS unsigned short* lp =
                (LDS_AS unsigned short*)&ldsA[0][(i * 32 + wid * 8) * BK];
            __builtin_amdgcn_global_load_lds((const GLOBAL_AS void*)gp,
                                             (LDS_AS void*)lp, 16, 0, 0);
        }
        const float s = s1_lds[prow][0];
        *(bf16x8*)&ldsB[0][prow * BPAD + pc8] = qdq8(b0, b1, s);
        asm volatile("s_waitcnt vmcnt(0)" ::: "memory");
        __syncthreads();
    }

    for (int t = 0; t < KCHUNKS; ++t) {
        const int cur = t & 1;
        const int nxt = cur ^ 1;
        const bool has_next = (t + 1 < KCHUNKS);

        float4 b0, b1;
        if (has_next) {
            const int k0n = (t + 1) * BK;
            // B fp32 loads first (their implied wait leaves A loads in flight)
            b0 = *(const float4*)(wB + k0n);
            b1 = *(const float4*)(wB + k0n + 4);
            for (int i = 0; i < 4; ++i) {
                const unsigned short* gp =
                    A + (size_t)(i * 32 + wid * 8 + r8) * IN_CH + k0n + sg * 8;
                LDS_AS unsigned short* lp =
                    (LDS_AS unsigned short*)&ldsA[nxt][(i * 32 + wid * 8) * BK];
                __builtin_amdgcn_global_load_lds((const GLOBAL_AS void*)gp,
                                                 (LDS_AS void*)lp, 16, 0, 0);
            }
        }

        // MFMA over the 64-deep chunk in buffer `cur`
        for (int kk = 0; kk < 2; ++kk) {
            bf16x8 af[4], bfv;
            const int ko = kk * 32 + quad * 8;              // logical k offset
            for (int i = 0; i < 4; ++i) {
                const int row = wm * 64 + i * 16 + lane15;
                const int pg = ((kk * 4 + quad) ^ (row & 7)) * 8;  // physical
                af[i] = *(const bf16x8*)&ldsA[cur][row * BK + pg];
            }
            bfv = *(const bf16x8*)&ldsB[cur][(wn * 16 + lane15) * BPAD + ko];
            for (int i = 0; i < 4; ++i)
                acc[i] = __builtin_amdgcn_mfma_f32_16x16x32_bf16(
                    af[i], bfv, acc[i], 0, 0, 0);
        }

        if (has_next) {
            // dequant t+1 (fp32 load latency hidden under the MFMAs above)
            const float s = s1_lds[prow][t + 1];
            *(bf16x8*)&ldsB[nxt][prow * BPAD + pc8] = qdq8(b0, b1, s);
            asm volatile("s_waitcnt vmcnt(0)" ::: "memory");
        }
        __syncthreads();
    }

    // ---- epilogue: out = acc + bias; C/D layout col=lane&15, row=quad*4+reg
    const int m_base = wm * 64 + quad * 4;
    const int nn = n0 + wn * 16 + lane15;
    const float bv = bias[nn];
    for (int i = 0; i < 4; ++i) {
        float* cp = out + (size_t)(m_base + i * 16) * OUT_CH + nn;
        cp[0 * OUT_CH] = acc[i][0] + bv;
        cp[1 * OUT_CH] = acc[i][1] + bv;
        cp[2 * OUT_CH] = acc[i][2] + bv;
        cp[3 * OUT_CH] = acc[i][3] + bv;
    }
}

extern "C" void kernel_launch(void* const* d_in, const int* in_sizes, int n_in,
                              void* d_out, int out_size, void* d_ws, size_t ws_size,
                              hipStream_t stream) {
    const float* x = (const float*)d_in[0];       // (1,128,4096) fp32
    const float* weight = (const float*)d_in[1];  // (11008,4096) fp32
    const float* bias = (const float*)d_in[2];    // (11008,) fp32
    float* out = (float*)d_out;                   // (1,128,11008) fp32

    // workspace: only the bf16-swizzled x (1 MB)
    unsigned short* wsX = (unsigned short*)d_ws;

    xconv_kernel<<<XCONV_BLOCKS, 256, 0, stream>>>(x, wsX);
    fused_kernel<<<NBLOCKS, 256, 0, stream>>>(weight, wsX, bias, out);
}

// Round 4
// 309.025 us; speedup vs baseline: 1.0698x; 1.0698x over previous
//
#include <hip/hip_runtime.h>
#include <hip/hip_bf16.h>

#define IN_CH 4096
#define OUT_CH 11008
#define QBLK 64

#define BM 128
#define BN 64
#define BK 64
#define KCHUNKS (IN_CH / BK)            // 64
#define KSPLIT 4
#define SPLIT_CHUNKS (KCHUNKS / KSPLIT) // 16
#define NTILES (OUT_CH / BN)            // 172
#define XCONV_BLOCKS 16

typedef short bf16x8 __attribute__((ext_vector_type(8)));
typedef float f32x4 __attribute__((ext_vector_type(4)));

#define GLOBAL_AS __attribute__((address_space(1)))
#define LDS_AS __attribute__((address_space(3)))

__device__ inline unsigned short f2bf(float f) {
    union { __hip_bfloat16 h; unsigned short u; } cv;
    cv.h = __float2bfloat16(f);
    return cv.u;
}

// unpack 8 int4 (two's-complement nibbles, lo nibble = even element) from a
// u32 and dequantize by s1 into 8 bf16. Same math as the verified round-1 path.
__device__ inline bf16x8 unpack8(unsigned v, float s1) {
    bf16x8 o;
#pragma unroll
    for (int i = 0; i < 4; ++i) {
        const int byte = (int)((v >> (8 * i)) & 0xFF);
        const int lo = (byte << 28) >> 28;   // sign-extended low nibble
        const int hi = (byte << 24) >> 28;   // sign-extended high nibble
        o[2 * i]     = (short)f2bf((float)lo * s1);
        o[2 * i + 1] = (short)f2bf((float)hi * s1);
    }
    return o;
}

// ---------------------------------------------------------------------------
// Kernel 1: LPBQ quantize of weight -> PACKED int4 w_q + fp32 s1r in
// row-major [row][64] layout (coalesced 256B store per row).
// Blocks [OUT_CH, OUT_CH+16) convert x -> bf16 with the XOR-swizzled granule
// layout so global_load_lds's rigid lane->LDS mapping yields bank-conflict-
// free A fragment reads in the GEMM.
// ---------------------------------------------------------------------------
__global__ __launch_bounds__(256) void quant_kernel(
        const float* __restrict__ w, const float* __restrict__ x,
        signed char* __restrict__ wq, float* __restrict__ s1rA,
        unsigned short* __restrict__ xq) {
    const int tid = threadIdx.x;

    if (blockIdx.x >= OUT_CH) {
        // ---- x fp32 -> bf16, swizzled. 65536 granules of 8 el. ----
        const int bx = blockIdx.x - OUT_CH;
        for (int it = 0; it < 16; ++it) {
            const int G = it * 4096 + bx * 256 + tid;   // granule id
            const int row = G >> 9;                     // 512 granules/row
            const int gi = G & 511;                     // granule in row
            const int kc = gi >> 3;
            const int gp = gi & 7;
            const int gl = gp ^ (row & 7);              // logical granule
            const float4* src =
                (const float4*)(x + (size_t)row * IN_CH + kc * 64 + gl * 8);
            float4 a = src[0], b = src[1];
            ushort4 o0, o1;
            o0.x = f2bf(a.x); o0.y = f2bf(a.y); o0.z = f2bf(a.z); o0.w = f2bf(a.w);
            o1.x = f2bf(b.x); o1.y = f2bf(b.y); o1.z = f2bf(b.z); o1.w = f2bf(b.w);
            ushort4* dst = (ushort4*)(xq + (size_t)row * IN_CH + gi * 8);
            dst[0] = o0;
            dst[1] = o1;
        }
        return;
    }

    const int row = blockIdx.x;
    const float* wrow = w + (size_t)row * IN_CH;
    signed char* orow = wq + (size_t)row * (IN_CH / 2);   // packed row: 2048 B

    __shared__ float s1_lds[64];   // pass A: s1; after pass B: s1r

    float4 v[4];
    const int lane16 = tid & 15;

    // Pass A: per-64-block max|.| -> s1 (16 lanes per quant-block)
    for (int p = 0; p < 4; ++p) {
        v[p] = ((const float4*)wrow)[p * 256 + tid];
        float m = fmaxf(fmaxf(fabsf(v[p].x), fabsf(v[p].y)),
                        fmaxf(fabsf(v[p].z), fabsf(v[p].w)));
        m = fmaxf(m, __shfl_xor(m, 1));
        m = fmaxf(m, __shfl_xor(m, 2));
        m = fmaxf(m, __shfl_xor(m, 4));
        m = fmaxf(m, __shfl_xor(m, 8));
        if (lane16 == 0)
            s1_lds[p * 16 + (tid >> 4)] = fmaxf(m * (1.0f / 7.0f), 1e-8f);
    }
    __syncthreads();

    // Pass B: s2 = clip(max_b s1 / 15, 1e-8); then s1r = clip(rint(s1/s2))*s2
    if (tid < 64) {
        float s1 = s1_lds[tid];
        float m = s1;
        m = fmaxf(m, __shfl_xor(m, 1));
        m = fmaxf(m, __shfl_xor(m, 2));
        m = fmaxf(m, __shfl_xor(m, 4));
        m = fmaxf(m, __shfl_xor(m, 8));
        m = fmaxf(m, __shfl_xor(m, 16));
        m = fmaxf(m, __shfl_xor(m, 32));
        const float s2 = fmaxf(m * (1.0f / 15.0f), 1e-8f);
        const float s1q = fminf(fmaxf(rintf(s1 / s2), 0.0f), 15.0f);
        const float s1r = s1q * s2;
        s1_lds[tid] = s1r;
        s1rA[(size_t)row * QBLK + tid] = s1r;   // coalesced 256B row store
    }
    __syncthreads();

    // Pass C: w_q = clip(rint(w / s1r), -8, 7), packed two nibbles per byte.
    for (int p = 0; p < 4; ++p) {
        const float s1r = s1_lds[p * 16 + (tid >> 4)];
        const int q0 = (int)fminf(fmaxf(rintf(v[p].x / s1r), -8.0f), 7.0f);
        const int q1 = (int)fminf(fmaxf(rintf(v[p].y / s1r), -8.0f), 7.0f);
        const int q2 = (int)fminf(fmaxf(rintf(v[p].z / s1r), -8.0f), 7.0f);
        const int q3 = (int)fminf(fmaxf(rintf(v[p].w / s1r), -8.0f), 7.0f);
        char2 o;
        o.x = (signed char)((q0 & 0xF) | ((q1 & 0xF) << 4));
        o.y = (signed char)((q2 & 0xF) | ((q3 & 0xF) << 4));
        ((char2*)orow)[p * 256 + tid] = o;
    }
}

// ---------------------------------------------------------------------------
// Kernel 2: K-split GEMM. A staged via global_load_lds w=16 from the
// XOR-swizzled xq (double-buffered, un-swizzle pg = (kk*4+quad)^(row&7)).
// B is loaded int4 DIRECTLY into per-lane registers (1 dword = 8 nibbles per
// MFMA fragment) and dequantized in-register -- no ldsB, no B ds_write/read,
// LDS 32 KB -> 4 blocks/CU. B(t+1) loads issue at the top of the iteration
// so the bottom vmcnt(0) (required for A's global_load_lds) finds them done.
// ---------------------------------------------------------------------------
__global__ __launch_bounds__(256, 4) void gemm_kernel(
        const unsigned short* __restrict__ A, const signed char* __restrict__ WQ4,
        const float* __restrict__ s1rA, float* __restrict__ part) {
    __shared__ __align__(16) unsigned short ldsA[2][BM * BK];   // 2 x 16 KB

    const int tid = threadIdx.x;
    const int wid = tid >> 6;
    const int l = tid & 63;
    const int wm = wid >> 1;     // 0..1: 64-row half of A
    const int wn = wid & 1;      // 0..1: 32-row half of B
    const int n0 = blockIdx.x * BN;
    const int kc0 = blockIdx.y * SPLIT_CHUNKS;

    const int r8 = l >> 3;       // A staging: row within 8-row group
    const int sg = l & 7;        // A staging: 16B segment in 128B row
    const int lane15 = l & 15;
    const int quad = l >> 4;

    f32x4 acc[4][2] = {};

    // B fragment rows for this lane (j=0,1)
    const int brow0 = n0 + wn * 32 + lane15;
    const int brow1 = brow0 + 16;
    const signed char* bq0 = WQ4 + (size_t)brow0 * (IN_CH / 2) + quad * 4;
    const signed char* bq1 = WQ4 + (size_t)brow1 * (IN_CH / 2) + quad * 4;
    const float* sp0 = s1rA + (size_t)brow0 * QBLK;
    const float* sp1 = s1rA + (size_t)brow1 * QBLK;

    // current-chunk B nibbles + scales (register double-buffer via rotation)
    unsigned cb00, cb01, cb10, cb11;   // [j][kk]
    float cs0, cs1;

    // ---------------- prologue: stage chunk kc0 ----------------
    {
        const int boff = kc0 * 32;
        cb00 = *(const unsigned*)(bq0 + boff);
        cb01 = *(const unsigned*)(bq0 + boff + 16);
        cb10 = *(const unsigned*)(bq1 + boff);
        cb11 = *(const unsigned*)(bq1 + boff + 16);
        cs0 = sp0[kc0];
        cs1 = sp1[kc0];
        const int k0 = kc0 * BK;
        for (int i = 0; i < 4; ++i) {
            const unsigned short* gp =
                A + (size_t)(i * 32 + wid * 8 + r8) * IN_CH + k0 + sg * 8;
            LDS_AS unsigned short* lp =
                (LDS_AS unsigned short*)&ldsA[0][(i * 32 + wid * 8) * BK];
            __builtin_amdgcn_global_load_lds((const GLOBAL_AS void*)gp,
                                             (LDS_AS void*)lp, 16, 0, 0);
        }
        asm volatile("s_waitcnt vmcnt(0)" ::: "memory");
        __syncthreads();
    }

    for (int t = 0; t < SPLIT_CHUNKS; ++t) {
        const int cur = t & 1;
        const int nxt = cur ^ 1;
        const bool has_next = (t + 1 < SPLIT_CHUNKS);

        unsigned nb00, nb01, nb10, nb11;
        float ns0, ns1;
        if (has_next) {
            const int kcn = kc0 + t + 1;
            const int boff = kcn * 32;
            // B(t+1) first: long time-of-flight before the bottom vmcnt(0)
            nb00 = *(const unsigned*)(bq0 + boff);
            nb01 = *(const unsigned*)(bq0 + boff + 16);
            nb10 = *(const unsigned*)(bq1 + boff);
            nb11 = *(const unsigned*)(bq1 + boff + 16);
            ns0 = sp0[kcn];
            ns1 = sp1[kcn];
            const int k0n = kcn * BK;
            for (int i = 0; i < 4; ++i) {
                const unsigned short* gp =
                    A + (size_t)(i * 32 + wid * 8 + r8) * IN_CH + k0n + sg * 8;
                LDS_AS unsigned short* lp =
                    (LDS_AS unsigned short*)&ldsA[nxt][(i * 32 + wid * 8) * BK];
                __builtin_amdgcn_global_load_lds((const GLOBAL_AS void*)gp,
                                                 (LDS_AS void*)lp, 16, 0, 0);
            }
        }

        // ---- dequant current B in-register (same bytes/order as LDS path) --
        bf16x8 bf00 = unpack8(cb00, cs0);   // j=0, kk=0
        bf16x8 bf01 = unpack8(cb01, cs0);   // j=0, kk=1
        bf16x8 bf10 = unpack8(cb10, cs1);   // j=1, kk=0
        bf16x8 bf11 = unpack8(cb11, cs1);   // j=1, kk=1

        // ---- MFMA over the 64-deep chunk in buffer `cur` ----
        for (int kk = 0; kk < 2; ++kk) {
            bf16x8 af[4];
            for (int i = 0; i < 4; ++i) {
                const int row = wm * 64 + i * 16 + lane15;
                const int pg = ((kk * 4 + quad) ^ (row & 7)) * 8;  // physical
                af[i] = *(const bf16x8*)&ldsA[cur][row * BK + pg];
            }
            const bf16x8 b0 = kk ? bf01 : bf00;
            const bf16x8 b1 = kk ? bf11 : bf10;
            for (int i = 0; i < 4; ++i) {
                acc[i][0] = __builtin_amdgcn_mfma_f32_16x16x32_bf16(
                    af[i], b0, acc[i][0], 0, 0, 0);
                acc[i][1] = __builtin_amdgcn_mfma_f32_16x16x32_bf16(
                    af[i], b1, acc[i][1], 0, 0, 0);
            }
        }

        if (has_next) {
            cb00 = nb00; cb01 = nb01; cb10 = nb10; cb11 = nb11;
            cs0 = ns0; cs1 = ns1;
            asm volatile("s_waitcnt vmcnt(0)" ::: "memory");
        }
        __syncthreads();
    }

    // ---- epilogue: partial store, C/D layout col=lane&15, row=quad*4+reg ----
    float* pbase = part + (size_t)blockIdx.y * BM * OUT_CH;
    const int m_base = wm * 64 + quad * 4;
    const int n_base = n0 + wn * 32 + lane15;
    for (int j = 0; j < 2; ++j) {
        for (int i = 0; i < 4; ++i) {
            const int m = m_base + i * 16;
            float* cp = pbase + (size_t)m * OUT_CH + n_base + j * 16;
            cp[0 * OUT_CH] = acc[i][j][0];
            cp[1 * OUT_CH] = acc[i][j][1];
            cp[2 * OUT_CH] = acc[i][j][2];
            cp[3 * OUT_CH] = acc[i][j][3];
        }
    }
}

// ---------------------------------------------------------------------------
// Kernel 3: reduce K-split partials + bias. Grid (11, 128) x 256 thr, float4.
// ---------------------------------------------------------------------------
__global__ __launch_bounds__(256) void reduce_kernel(
        const float* __restrict__ part, const float* __restrict__ bias,
        float* __restrict__ out) {
    const int m = blockIdx.y;
    const int x4 = blockIdx.x * 256 + threadIdx.x;
    if (x4 >= OUT_CH / 4) return;
    const size_t off = (size_t)m * OUT_CH + x4 * 4;

    float4 acc = ((const float4*)bias)[x4];
    for (int s = 0; s < KSPLIT; ++s) {
        float4 p = *(const float4*)(part + (size_t)s * BM * OUT_CH + off);
        acc.x += p.x; acc.y += p.y; acc.z += p.z; acc.w += p.w;
    }
    *(float4*)(out + off) = acc;
}

extern "C" void kernel_launch(void* const* d_in, const int* in_sizes, int n_in,
                              void* d_out, int out_size, void* d_ws, size_t ws_size,
                              hipStream_t stream) {
    const float* x = (const float*)d_in[0];       // (1,128,4096) fp32
    const float* weight = (const float*)d_in[1];  // (11008,4096) fp32
    const float* bias = (const float*)d_in[2];    // (11008,) fp32
    float* out = (float*)d_out;                   // (1,128,11008) fp32

    // workspace layout (16B-aligned slices)
    signed char* wsQ = (signed char*)d_ws;                              // 22.5 MB int4 w_q (packed)
    unsigned short* wsX = (unsigned short*)(wsQ + (size_t)OUT_CH * (IN_CH / 2)); // 1 MB bf16 x (swizzled)
    float* wsS = (float*)(wsX + (size_t)BM * IN_CH);                    // 2.8 MB s1r [row][64]
    float* wsP = wsS + (size_t)OUT_CH * QBLK;                           // 22.5 MB partials

    quant_kernel<<<OUT_CH + XCONV_BLOCKS, 256, 0, stream>>>(weight, x, wsQ, wsS, wsX);
    gemm_kernel<<<dim3(NTILES, KSPLIT), 256, 0, stream>>>(wsX, wsQ, wsS, wsP);
    reduce_kernel<<<dim3((OUT_CH / 4 + 255) / 256, BM), 256, 0, stream>>>(
        wsP, bias, out);
}

// Round 5
// 303.681 us; speedup vs baseline: 1.0886x; 1.0176x over previous
//
#include <hip/hip_runtime.h>
#include <hip/hip_bf16.h>

#define IN_CH 4096
#define OUT_CH 11008
#define QBLK 64

#define BM 128
#define BN 64
#define BK 64
#define KCHUNKS (IN_CH / BK)            // 64
#define KSPLIT 4
#define SPLIT_CHUNKS (KCHUNKS / KSPLIT) // 16
#define NTILES (OUT_CH / BN)            // 172
#define XCONV_BLOCKS 16
#define BIAS_BLOCKS 16
#define BPAD 72                          // B LDS row stride (64 + 8 pad)

typedef short bf16x8 __attribute__((ext_vector_type(8)));
typedef float f32x4 __attribute__((ext_vector_type(4)));

#define GLOBAL_AS __attribute__((address_space(1)))
#define LDS_AS __attribute__((address_space(3)))

__device__ inline unsigned short f2bf(float f) {
    union { __hip_bfloat16 h; unsigned short u; } cv;
    cv.h = __float2bfloat16(f);
    return cv.u;
}

// unpack 8 int4 (two's-complement nibbles, lo nibble = even element) from a
// u32 and dequantize by s1 into 8 bf16 (verified round-1 path).
__device__ inline void unpack8(unsigned v, float s1, bf16x8& o) {
#pragma unroll
    for (int i = 0; i < 4; ++i) {
        const int byte = (int)((v >> (8 * i)) & 0xFF);
        const int lo = (byte << 28) >> 28;   // sign-extended low nibble
        const int hi = (byte << 24) >> 28;   // sign-extended high nibble
        o[2 * i]     = (short)f2bf((float)lo * s1);
        o[2 * i + 1] = (short)f2bf((float)hi * s1);
    }
}

// ---------------------------------------------------------------------------
// Kernel 1: LPBQ quantize of weight -> PACKED int4 w_q + fp32 s1r in
// coalesced row-major [row][64] layout (256B store per row, no scatter).
// Blocks [OUT_CH, OUT_CH+16): x -> bf16 XOR-swizzled granule layout (for
// conflict-free global_load_lds A fragments in the GEMM).
// Blocks [OUT_CH+16, OUT_CH+32): out = broadcast(bias) init, so the GEMM can
// accumulate with f32 atomics (no partials buffer, no reduce kernel).
// ---------------------------------------------------------------------------
__global__ __launch_bounds__(256) void quant_kernel(
        const float* __restrict__ w, const float* __restrict__ x,
        const float* __restrict__ bias, signed char* __restrict__ wq,
        float* __restrict__ s1rA, unsigned short* __restrict__ xq,
        float* __restrict__ out) {
    const int tid = threadIdx.x;

    if (blockIdx.x >= OUT_CH + XCONV_BLOCKS) {
        // ---- bias broadcast init of out: 352256 float4 total ----
        const int bx = blockIdx.x - OUT_CH - XCONV_BLOCKS;
        const float4* b4 = (const float4*)bias;
        float4* o4 = (float4*)out;
        for (int q = bx * 256 + tid; q < BM * OUT_CH / 4;
             q += BIAS_BLOCKS * 256)
            o4[q] = b4[q % (OUT_CH / 4)];
        return;
    }

    if (blockIdx.x >= OUT_CH) {
        // ---- x fp32 -> bf16, swizzled. 65536 granules of 8 el. ----
        const int bx = blockIdx.x - OUT_CH;
        for (int it = 0; it < 16; ++it) {
            const int G = it * 4096 + bx * 256 + tid;   // granule id
            const int row = G >> 9;                     // 512 granules/row
            const int gi = G & 511;                     // granule in row
            const int kc = gi >> 3;
            const int gp = gi & 7;
            const int gl = gp ^ (row & 7);              // logical granule
            const float4* src =
                (const float4*)(x + (size_t)row * IN_CH + kc * 64 + gl * 8);
            float4 a = src[0], b = src[1];
            ushort4 o0, o1;
            o0.x = f2bf(a.x); o0.y = f2bf(a.y); o0.z = f2bf(a.z); o0.w = f2bf(a.w);
            o1.x = f2bf(b.x); o1.y = f2bf(b.y); o1.z = f2bf(b.z); o1.w = f2bf(b.w);
            ushort4* dst = (ushort4*)(xq + (size_t)row * IN_CH + gi * 8);
            dst[0] = o0;
            dst[1] = o1;
        }
        return;
    }

    const int row = blockIdx.x;
    const float* wrow = w + (size_t)row * IN_CH;
    signed char* orow = wq + (size_t)row * (IN_CH / 2);   // packed row: 2048 B

    __shared__ float s1_lds[64];   // pass A: s1; after pass B: s1r

    float4 v[4];
    const int lane16 = tid & 15;

    // Pass A: per-64-block max|.| -> s1 (16 lanes per quant-block)
    for (int p = 0; p < 4; ++p) {
        v[p] = ((const float4*)wrow)[p * 256 + tid];
        float m = fmaxf(fmaxf(fabsf(v[p].x), fabsf(v[p].y)),
                        fmaxf(fabsf(v[p].z), fabsf(v[p].w)));
        m = fmaxf(m, __shfl_xor(m, 1));
        m = fmaxf(m, __shfl_xor(m, 2));
        m = fmaxf(m, __shfl_xor(m, 4));
        m = fmaxf(m, __shfl_xor(m, 8));
        if (lane16 == 0)
            s1_lds[p * 16 + (tid >> 4)] = fmaxf(m * (1.0f / 7.0f), 1e-8f);
    }
    __syncthreads();

    // Pass B: s2 = clip(max_b s1 / 15, 1e-8); then s1r = clip(rint(s1/s2))*s2
    if (tid < 64) {
        float s1 = s1_lds[tid];
        float m = s1;
        m = fmaxf(m, __shfl_xor(m, 1));
        m = fmaxf(m, __shfl_xor(m, 2));
        m = fmaxf(m, __shfl_xor(m, 4));
        m = fmaxf(m, __shfl_xor(m, 8));
        m = fmaxf(m, __shfl_xor(m, 16));
        m = fmaxf(m, __shfl_xor(m, 32));
        const float s2 = fmaxf(m * (1.0f / 15.0f), 1e-8f);
        const float s1q = fminf(fmaxf(rintf(s1 / s2), 0.0f), 15.0f);
        const float s1r = s1q * s2;
        s1_lds[tid] = s1r;
        s1rA[(size_t)row * QBLK + tid] = s1r;   // coalesced 256B row store
    }
    __syncthreads();

    // Pass C: w_q = clip(rint(w / s1r), -8, 7), packed two nibbles per byte.
    for (int p = 0; p < 4; ++p) {
        const float s1r = s1_lds[p * 16 + (tid >> 4)];
        const int q0 = (int)fminf(fmaxf(rintf(v[p].x / s1r), -8.0f), 7.0f);
        const int q1 = (int)fminf(fmaxf(rintf(v[p].y / s1r), -8.0f), 7.0f);
        const int q2 = (int)fminf(fmaxf(rintf(v[p].z / s1r), -8.0f), 7.0f);
        const int q3 = (int)fminf(fmaxf(rintf(v[p].w / s1r), -8.0f), 7.0f);
        char2 o;
        o.x = (signed char)((q0 & 0xF) | ((q1 & 0xF) << 4));
        o.y = (signed char)((q2 & 0xF) | ((q3 & 0xF) << 4));
        ((char2*)orow)[p * 256 + tid] = o;
    }
}

// ---------------------------------------------------------------------------
// Kernel 2: K-split GEMM (round-1 proven structure). A staged via
// global_load_lds w=16 from the XOR-swizzled xq; B int4 reg-loaded, dequanted
// to bf16 in padded ldsB (broadcast reuse); double-buffered 2-phase pipeline
// (STAGE(t+1) issued before MFMA(t), B ds_write after the MFMAs). Epilogue
// accumulates directly into bias-initialized out via hardware f32 atomics.
// ---------------------------------------------------------------------------
__global__ __launch_bounds__(256) void gemm_kernel(
        const unsigned short* __restrict__ A, const signed char* __restrict__ WQ4,
        const float* __restrict__ s1rA, float* __restrict__ out) {
    __shared__ __align__(16) unsigned short ldsA[2][BM * BK];   // 2 x 16 KB
    __shared__ __align__(16) unsigned short ldsB[2][BN * BPAD]; // 2 x 9 KB

    const int tid = threadIdx.x;
    const int w = tid >> 6;
    const int l = tid & 63;
    const int wm = w >> 1;
    const int wn = w & 1;
    const int n0 = blockIdx.x * BN;
    const int kc0 = blockIdx.y * SPLIT_CHUNKS;

    const int r8 = l >> 3;       // A staging: row within 8-row group
    const int sg = l & 7;        // A staging: 16B segment in 128B row

    const int brow = tid >> 2;   // B staging: row 0..63 (4 thr/row)
    const int bcg = tid & 3;     // B staging: 16-el col group

    const int lane15 = l & 15;
    const int quad = l >> 4;

    f32x4 acc[4][2] = {};

    const size_t bqBase = (size_t)(n0 + brow) * (IN_CH / 2) + bcg * 8;
    const float* sRow = s1rA + (size_t)(n0 + brow) * QBLK;

    // ---------------- prologue: stage chunk kc0 into buffer 0 ---------------
    {
        const int k0 = kc0 * BK;
        for (int i = 0; i < 4; ++i) {
            const unsigned short* gp =
                A + (size_t)(i * 32 + w * 8 + r8) * IN_CH + k0 + sg * 8;
            LDS_AS unsigned short* lp =
                (LDS_AS unsigned short*)&ldsA[0][(i * 32 + w * 8) * BK];
            __builtin_amdgcn_global_load_lds((const GLOBAL_AS void*)gp,
                                             (LDS_AS void*)lp, 16, 0, 0);
        }
        const float s1 = sRow[kc0];
        const uint2 bq = *(const uint2*)(WQ4 + bqBase + (size_t)kc0 * 32);
        bf16x8 o0, o1;
        unpack8(bq.x, s1, o0);
        unpack8(bq.y, s1, o1);
        *(bf16x8*)&ldsB[0][brow * BPAD + bcg * 16] = o0;
        *(bf16x8*)&ldsB[0][brow * BPAD + bcg * 16 + 8] = o1;
        asm volatile("s_waitcnt vmcnt(0)" ::: "memory");
        __syncthreads();
    }

    for (int t = 0; t < SPLIT_CHUNKS; ++t) {
        const int cur = t & 1;
        const int nxt = cur ^ 1;
        const bool has_next = (t + 1 < SPLIT_CHUNKS);

        uint2 bqn;
        float s1n;
        if (has_next) {
            const int kcn = kc0 + t + 1;
            const int k0n = kcn * BK;
            for (int i = 0; i < 4; ++i) {
                const unsigned short* gp =
                    A + (size_t)(i * 32 + w * 8 + r8) * IN_CH + k0n + sg * 8;
                LDS_AS unsigned short* lp =
                    (LDS_AS unsigned short*)&ldsA[nxt][(i * 32 + w * 8) * BK];
                __builtin_amdgcn_global_load_lds((const GLOBAL_AS void*)gp,
                                                 (LDS_AS void*)lp, 16, 0, 0);
            }
            s1n = sRow[kcn];
            bqn = *(const uint2*)(WQ4 + bqBase + (size_t)kcn * 32);
        }

        // ---- MFMA over the 64-deep chunk ----
        for (int kk = 0; kk < 2; ++kk) {
            bf16x8 af[4], bfv[2];
            const int ko = kk * 32 + quad * 8;          // logical k offset
            for (int i = 0; i < 4; ++i) {
                const int row = wm * 64 + i * 16 + lane15;
                const int pg = ((kk * 4 + quad) ^ (row & 7)) * 8;  // physical
                af[i] = *(const bf16x8*)&ldsA[cur][row * BK + pg];
            }
            for (int j = 0; j < 2; ++j)
                bfv[j] = *(const bf16x8*)&ldsB[cur][(wn * 32 + j * 16 + lane15) * BPAD + ko];
            for (int i = 0; i < 4; ++i)
                for (int j = 0; j < 2; ++j)
                    acc[i][j] = __builtin_amdgcn_mfma_f32_16x16x32_bf16(
                        af[i], bfv[j], acc[i][j], 0, 0, 0);
        }

        if (has_next) {
            bf16x8 o0, o1;
            unpack8(bqn.x, s1n, o0);
            unpack8(bqn.y, s1n, o1);
            *(bf16x8*)&ldsB[nxt][brow * BPAD + bcg * 16] = o0;
            *(bf16x8*)&ldsB[nxt][brow * BPAD + bcg * 16 + 8] = o1;
            asm volatile("s_waitcnt vmcnt(0)" ::: "memory");
        }
        __syncthreads();
    }

    // ---- epilogue: atomic accumulate into bias-initialized out ----
    // C/D layout col=lane&15, row=quad*4+reg
    const int m_base = wm * 64 + quad * 4;
    const int n_base = n0 + wn * 32 + lane15;
    for (int j = 0; j < 2; ++j) {
        for (int i = 0; i < 4; ++i) {
            const int m = m_base + i * 16;
            float* cp = out + (size_t)m * OUT_CH + n_base + j * 16;
            unsafeAtomicAdd(cp + 0 * OUT_CH, acc[i][j][0]);
            unsafeAtomicAdd(cp + 1 * OUT_CH, acc[i][j][1]);
            unsafeAtomicAdd(cp + 2 * OUT_CH, acc[i][j][2]);
            unsafeAtomicAdd(cp + 3 * OUT_CH, acc[i][j][3]);
        }
    }
}

extern "C" void kernel_launch(void* const* d_in, const int* in_sizes, int n_in,
                              void* d_out, int out_size, void* d_ws, size_t ws_size,
                              hipStream_t stream) {
    const float* x = (const float*)d_in[0];       // (1,128,4096) fp32
    const float* weight = (const float*)d_in[1];  // (11008,4096) fp32
    const float* bias = (const float*)d_in[2];    // (11008,) fp32
    float* out = (float*)d_out;                   // (1,128,11008) fp32

    // workspace layout (16B-aligned slices)
    signed char* wsQ = (signed char*)d_ws;                              // 22.5 MB int4 w_q (packed)
    unsigned short* wsX = (unsigned short*)(wsQ + (size_t)OUT_CH * (IN_CH / 2)); // 1 MB bf16 x (swizzled)
    float* wsS = (float*)(wsX + (size_t)BM * IN_CH);                    // 2.8 MB s1r [row][64]

    quant_kernel<<<OUT_CH + XCONV_BLOCKS + BIAS_BLOCKS, 256, 0, stream>>>(
        weight, x, bias, wsQ, wsS, wsX, out);
    gemm_kernel<<<dim3(NTILES, KSPLIT), 256, 0, stream>>>(wsX, wsQ, wsS, out);
}

// Round 6
// 291.389 us; speedup vs baseline: 1.1346x; 1.0422x over previous
//
#include <hip/hip_runtime.h>
#include <hip/hip_bf16.h>

#define IN_CH 4096
#define OUT_CH 11008
#define QBLK 64

#define BM 128
#define BN 64
#define BK 64
#define KCHUNKS (IN_CH / BK)            // 64
#define KSPLIT 4
#define SPLIT_CHUNKS (KCHUNKS / KSPLIT) // 16
#define NTILES (OUT_CH / BN)            // 172
#define XCONV_BLOCKS 16
#define BPAD 72                          // B LDS row stride (64 + 8 pad)

typedef short bf16x8 __attribute__((ext_vector_type(8)));
typedef float f32x4 __attribute__((ext_vector_type(4)));

#define GLOBAL_AS __attribute__((address_space(1)))
#define LDS_AS __attribute__((address_space(3)))

__device__ inline unsigned short f2bf(float f) {
    union { __hip_bfloat16 h; unsigned short u; } cv;
    cv.h = __float2bfloat16(f);
    return cv.u;
}

// unpack 8 int4 (two's-complement nibbles, lo nibble = even element) from a
// u32 and dequantize by s1 into 8 bf16 (verified round-1 path).
__device__ inline void unpack8(unsigned v, float s1, bf16x8& o) {
#pragma unroll
    for (int i = 0; i < 4; ++i) {
        const int byte = (int)((v >> (8 * i)) & 0xFF);
        const int lo = (byte << 28) >> 28;   // sign-extended low nibble
        const int hi = (byte << 24) >> 28;   // sign-extended high nibble
        o[2 * i]     = (short)f2bf((float)lo * s1);
        o[2 * i + 1] = (short)f2bf((float)hi * s1);
    }
}

// ---------------------------------------------------------------------------
// Kernel 1: LPBQ quantize of weight -> PACKED int4 w_q + fp32 s1r in
// coalesced row-major [row][64] layout (one contiguous 256B store per row --
// replaces the r1 s1rT scatter that dirtied 64 lines/row => ~45MB of writes).
// Blocks [OUT_CH, OUT_CH+16) convert x -> bf16 with the XOR-swizzled granule
// layout so global_load_lds's rigid lane->LDS mapping yields bank-conflict-
// free A fragment reads in the GEMM.
// ---------------------------------------------------------------------------
__global__ __launch_bounds__(256) void quant_kernel(
        const float* __restrict__ w, const float* __restrict__ x,
        signed char* __restrict__ wq, float* __restrict__ s1rA,
        unsigned short* __restrict__ xq) {
    const int tid = threadIdx.x;

    if (blockIdx.x >= OUT_CH) {
        // ---- x fp32 -> bf16, swizzled. 65536 granules of 8 el. ----
        const int bx = blockIdx.x - OUT_CH;
        for (int it = 0; it < 16; ++it) {
            const int G = it * 4096 + bx * 256 + tid;   // granule id
            const int row = G >> 9;                     // 512 granules/row
            const int gi = G & 511;                     // granule in row
            const int kc = gi >> 3;
            const int gp = gi & 7;
            const int gl = gp ^ (row & 7);              // logical granule
            const float4* src =
                (const float4*)(x + (size_t)row * IN_CH + kc * 64 + gl * 8);
            float4 a = src[0], b = src[1];
            ushort4 o0, o1;
            o0.x = f2bf(a.x); o0.y = f2bf(a.y); o0.z = f2bf(a.z); o0.w = f2bf(a.w);
            o1.x = f2bf(b.x); o1.y = f2bf(b.y); o1.z = f2bf(b.z); o1.w = f2bf(b.w);
            ushort4* dst = (ushort4*)(xq + (size_t)row * IN_CH + gi * 8);
            dst[0] = o0;
            dst[1] = o1;
        }
        return;
    }

    const int row = blockIdx.x;
    const float* wrow = w + (size_t)row * IN_CH;
    signed char* orow = wq + (size_t)row * (IN_CH / 2);   // packed row: 2048 B

    __shared__ float s1_lds[64];   // pass A: s1; after pass B: s1r

    float4 v[4];
    const int lane16 = tid & 15;

    // Pass A: per-64-block max|.| -> s1 (16 lanes per quant-block)
    for (int p = 0; p < 4; ++p) {
        v[p] = ((const float4*)wrow)[p * 256 + tid];
        float m = fmaxf(fmaxf(fabsf(v[p].x), fabsf(v[p].y)),
                        fmaxf(fabsf(v[p].z), fabsf(v[p].w)));
        m = fmaxf(m, __shfl_xor(m, 1));
        m = fmaxf(m, __shfl_xor(m, 2));
        m = fmaxf(m, __shfl_xor(m, 4));
        m = fmaxf(m, __shfl_xor(m, 8));
        if (lane16 == 0)
            s1_lds[p * 16 + (tid >> 4)] = fmaxf(m * (1.0f / 7.0f), 1e-8f);
    }
    __syncthreads();

    // Pass B: s2 = clip(max_b s1 / 15, 1e-8); then s1r = clip(rint(s1/s2))*s2
    if (tid < 64) {
        float s1 = s1_lds[tid];
        float m = s1;
        m = fmaxf(m, __shfl_xor(m, 1));
        m = fmaxf(m, __shfl_xor(m, 2));
        m = fmaxf(m, __shfl_xor(m, 4));
        m = fmaxf(m, __shfl_xor(m, 8));
        m = fmaxf(m, __shfl_xor(m, 16));
        m = fmaxf(m, __shfl_xor(m, 32));
        const float s2 = fmaxf(m * (1.0f / 15.0f), 1e-8f);
        const float s1q = fminf(fmaxf(rintf(s1 / s2), 0.0f), 15.0f);
        const float s1r = s1q * s2;
        s1_lds[tid] = s1r;
        s1rA[(size_t)row * QBLK + tid] = s1r;   // coalesced 256B row store
    }
    __syncthreads();

    // Pass C: w_q = clip(rint(w / s1r), -8, 7), packed two nibbles per byte.
    for (int p = 0; p < 4; ++p) {
        const float s1r = s1_lds[p * 16 + (tid >> 4)];
        const int q0 = (int)fminf(fmaxf(rintf(v[p].x / s1r), -8.0f), 7.0f);
        const int q1 = (int)fminf(fmaxf(rintf(v[p].y / s1r), -8.0f), 7.0f);
        const int q2 = (int)fminf(fmaxf(rintf(v[p].z / s1r), -8.0f), 7.0f);
        const int q3 = (int)fminf(fmaxf(rintf(v[p].w / s1r), -8.0f), 7.0f);
        char2 o;
        o.x = (signed char)((q0 & 0xF) | ((q1 & 0xF) << 4));
        o.y = (signed char)((q2 & 0xF) | ((q3 & 0xF) << 4));
        ((char2*)orow)[p * 256 + tid] = o;
    }
}

// ---------------------------------------------------------------------------
// Kernel 2: K-split GEMM (round-1 proven structure, unchanged except the
// coalesced s1r read). A staged via global_load_lds w=16 from the
// XOR-swizzled xq; B int4 reg-loaded, dequanted to bf16 into padded ldsB
// (broadcast reuse); double-buffered 2-phase pipeline: STAGE(t+1) issued
// before MFMA(t), B dequant+ds_write after the MFMAs (HBM latency hidden
// under compute); single vmcnt(0)+barrier per chunk. Fragment reads
// un-swizzle A with pg = (kk*4+quad)^(row&7) -> conflict-free.
// ---------------------------------------------------------------------------
__global__ __launch_bounds__(256) void gemm_kernel(
        const unsigned short* __restrict__ A, const signed char* __restrict__ WQ4,
        const float* __restrict__ s1rA, float* __restrict__ part) {
    __shared__ __align__(16) unsigned short ldsA[2][BM * BK];   // 2 x 16 KB
    __shared__ __align__(16) unsigned short ldsB[2][BN * BPAD]; // 2 x 9 KB

    const int tid = threadIdx.x;
    const int w = tid >> 6;
    const int l = tid & 63;
    const int wm = w >> 1;
    const int wn = w & 1;
    const int n0 = blockIdx.x * BN;
    const int kc0 = blockIdx.y * SPLIT_CHUNKS;

    const int r8 = l >> 3;       // A staging: row within 8-row group
    const int sg = l & 7;        // A staging: 16B segment in 128B row

    const int brow = tid >> 2;   // B staging: row 0..63 (4 thr/row)
    const int bcg = tid & 3;     // B staging: 16-el col group

    const int lane15 = l & 15;
    const int quad = l >> 4;

    f32x4 acc[4][2] = {};

    const size_t bqBase = (size_t)(n0 + brow) * (IN_CH / 2) + bcg * 8;
    const float* sRow = s1rA + (size_t)(n0 + brow) * QBLK;

    // ---------------- prologue: stage chunk kc0 into buffer 0 ---------------
    {
        const int k0 = kc0 * BK;
        for (int i = 0; i < 4; ++i) {
            const unsigned short* gp =
                A + (size_t)(i * 32 + w * 8 + r8) * IN_CH + k0 + sg * 8;
            LDS_AS unsigned short* lp =
                (LDS_AS unsigned short*)&ldsA[0][(i * 32 + w * 8) * BK];
            __builtin_amdgcn_global_load_lds((const GLOBAL_AS void*)gp,
                                             (LDS_AS void*)lp, 16, 0, 0);
        }
        const float s1 = sRow[kc0];
        const uint2 bq = *(const uint2*)(WQ4 + bqBase + (size_t)kc0 * 32);
        bf16x8 o0, o1;
        unpack8(bq.x, s1, o0);
        unpack8(bq.y, s1, o1);
        *(bf16x8*)&ldsB[0][brow * BPAD + bcg * 16] = o0;
        *(bf16x8*)&ldsB[0][brow * BPAD + bcg * 16 + 8] = o1;
        asm volatile("s_waitcnt vmcnt(0)" ::: "memory");
        __syncthreads();
    }

    for (int t = 0; t < SPLIT_CHUNKS; ++t) {
        const int cur = t & 1;
        const int nxt = cur ^ 1;
        const bool has_next = (t + 1 < SPLIT_CHUNKS);

        uint2 bqn;
        float s1n;
        if (has_next) {
            const int kcn = kc0 + t + 1;
            const int k0n = kcn * BK;
            // A tile t+1: async global -> LDS (other buffer)
            for (int i = 0; i < 4; ++i) {
                const unsigned short* gp =
                    A + (size_t)(i * 32 + w * 8 + r8) * IN_CH + k0n + sg * 8;
                LDS_AS unsigned short* lp =
                    (LDS_AS unsigned short*)&ldsA[nxt][(i * 32 + w * 8) * BK];
                __builtin_amdgcn_global_load_lds((const GLOBAL_AS void*)gp,
                                                 (LDS_AS void*)lp, 16, 0, 0);
            }
            // B tile t+1: issue the int4 load now; consume after the MFMAs.
            s1n = sRow[kcn];
            bqn = *(const uint2*)(WQ4 + bqBase + (size_t)kcn * 32);
        }

        // ---- MFMA over the 64-deep chunk in buffer `cur` ----
        for (int kk = 0; kk < 2; ++kk) {
            bf16x8 af[4], bfv[2];
            const int ko = kk * 32 + quad * 8;          // logical k offset
            for (int i = 0; i < 4; ++i) {
                const int row = wm * 64 + i * 16 + lane15;
                const int pg = ((kk * 4 + quad) ^ (row & 7)) * 8;  // physical
                af[i] = *(const bf16x8*)&ldsA[cur][row * BK + pg];
            }
            for (int j = 0; j < 2; ++j)
                bfv[j] = *(const bf16x8*)&ldsB[cur][(wn * 32 + j * 16 + lane15) * BPAD + ko];
            for (int i = 0; i < 4; ++i)
                for (int j = 0; j < 2; ++j)
                    acc[i][j] = __builtin_amdgcn_mfma_f32_16x16x32_bf16(
                        af[i], bfv[j], acc[i][j], 0, 0, 0);
        }

        if (has_next) {
            // Dequant t+1 (B load latency hidden under the MFMAs above) and
            // write to the other buffer; then drain A's global_load_lds.
            bf16x8 o0, o1;
            unpack8(bqn.x, s1n, o0);
            unpack8(bqn.y, s1n, o1);
            *(bf16x8*)&ldsB[nxt][brow * BPAD + bcg * 16] = o0;
            *(bf16x8*)&ldsB[nxt][brow * BPAD + bcg * 16 + 8] = o1;
            asm volatile("s_waitcnt vmcnt(0)" ::: "memory");
        }
        __syncthreads();
    }

    // ---- epilogue: partial store, C/D layout col=lane&15, row=quad*4+reg ----
    float* pbase = part + (size_t)blockIdx.y * BM * OUT_CH;
    const int m_base = wm * 64 + quad * 4;
    const int n_base = n0 + wn * 32 + lane15;
    for (int j = 0; j < 2; ++j) {
        for (int i = 0; i < 4; ++i) {
            const int m = m_base + i * 16;
            float* cp = pbase + (size_t)m * OUT_CH + n_base + j * 16;
            cp[0 * OUT_CH] = acc[i][j][0];
            cp[1 * OUT_CH] = acc[i][j][1];
            cp[2 * OUT_CH] = acc[i][j][2];
            cp[3 * OUT_CH] = acc[i][j][3];
        }
    }
}

// ---------------------------------------------------------------------------
// Kernel 3: reduce K-split partials + bias. Grid (11, 128) x 256 thr, float4.
// ---------------------------------------------------------------------------
__global__ __launch_bounds__(256) void reduce_kernel(
        const float* __restrict__ part, const float* __restrict__ bias,
        float* __restrict__ out) {
    const int m = blockIdx.y;
    const int x4 = blockIdx.x * 256 + threadIdx.x;
    if (x4 >= OUT_CH / 4) return;
    const size_t off = (size_t)m * OUT_CH + x4 * 4;

    float4 acc = ((const float4*)bias)[x4];
    for (int s = 0; s < KSPLIT; ++s) {
        float4 p = *(const float4*)(part + (size_t)s * BM * OUT_CH + off);
        acc.x += p.x; acc.y += p.y; acc.z += p.z; acc.w += p.w;
    }
    *(float4*)(out + off) = acc;
}

extern "C" void kernel_launch(void* const* d_in, const int* in_sizes, int n_in,
                              void* d_out, int out_size, void* d_ws, size_t ws_size,
                              hipStream_t stream) {
    const float* x = (const float*)d_in[0];       // (1,128,4096) fp32
    const float* weight = (const float*)d_in[1];  // (11008,4096) fp32
    const float* bias = (const float*)d_in[2];    // (11008,) fp32
    float* out = (float*)d_out;                   // (1,128,11008) fp32

    // workspace layout (16B-aligned slices)
    signed char* wsQ = (signed char*)d_ws;                              // 22.5 MB int4 w_q (packed)
    unsigned short* wsX = (unsigned short*)(wsQ + (size_t)OUT_CH * (IN_CH / 2)); // 1 MB bf16 x (swizzled)
    float* wsS = (float*)(wsX + (size_t)BM * IN_CH);                    // 2.8 MB s1r [row][64]
    float* wsP = wsS + (size_t)OUT_CH * QBLK;                           // 22.5 MB partials

    quant_kernel<<<OUT_CH + XCONV_BLOCKS, 256, 0, stream>>>(weight, x, wsQ, wsS, wsX);
    gemm_kernel<<<dim3(NTILES, KSPLIT), 256, 0, stream>>>(wsX, wsQ, wsS, wsP);
    reduce_kernel<<<dim3((OUT_CH / 4 + 255) / 256, BM), 256, 0, stream>>>(
        wsP, bias, out);
}